// Round 1
// baseline (190.565 us; speedup 1.0000x reference)
//
#include <hip/hip_runtime.h>
#include <math.h>

// MoE router: x[16384,2048] fp32, W[8,2048] fp32 -> (top2 idx, top2 gates, logits)
// Memory-bound: 134 MB read-once. Wave = 8 tokens; lane owns 4-dim strided chunks.

constexpr int D      = 2048;
constexpr int E      = 8;
constexpr int T      = 8;      // tokens per wave
constexpr int WAVES  = 4;      // waves per block (256 threads)
constexpr int TOKENS = 16384;

__device__ __forceinline__ bool better(float va, int ia, float vb, int ib) {
    // jax.lax.top_k tie rule: larger value wins; equal values -> smaller index
    return (va > vb) || (va == vb && ia < ib);
}

__global__ __launch_bounds__(256, 2)
void moe_router_kernel(const float* __restrict__ x,
                       const float* __restrict__ w,
                       float* __restrict__ out)
{
    // 64 pairs x 64 lanes, rotated columns for bank-conflict-free scatter+gather.
    __shared__ float scr[WAVES][64][64];   // 64 KiB -> 2 blocks/CU

    const int lane = threadIdx.x & 63;
    const int wave = threadIdx.x >> 6;
    const int tok0 = (blockIdx.x * WAVES + wave) * T;

    float acc[T * E];
#pragma unroll
    for (int i = 0; i < T * E; ++i) acc[i] = 0.0f;

    // K loop: 8 iterations cover D=2048. Lane l handles dims it*256 + l*4 .. +3.
#pragma unroll
    for (int it = 0; it < D / 256; ++it) {
        const int d = it * 256 + lane * 4;
        float4 wv[E];
#pragma unroll
        for (int e = 0; e < E; ++e)
            wv[e] = *reinterpret_cast<const float4*>(w + e * D + d);
        float4 xv[T];
#pragma unroll
        for (int t = 0; t < T; ++t)
            xv[t] = *reinterpret_cast<const float4*>(x + (size_t)(tok0 + t) * D + d);
#pragma unroll
        for (int t = 0; t < T; ++t) {
#pragma unroll
            for (int e = 0; e < E; ++e) {
                float a = acc[t * E + e];
                a = fmaf(xv[t].x, wv[e].x, a);
                a = fmaf(xv[t].y, wv[e].y, a);
                a = fmaf(xv[t].z, wv[e].z, a);
                a = fmaf(xv[t].w, wv[e].w, a);
                acc[t * E + e] = a;
            }
        }
    }

    // Scatter partials: row p = (token t = p>>3, expert e = p&7), rotated column.
#pragma unroll
    for (int p = 0; p < 64; ++p)
        scr[wave][p][(lane + p) & 63] = acc[p];

    __syncthreads();

    // Lane l reduces row l (its pair) over all 64 source lanes, rotated reads.
    float s0 = 0.f, s1 = 0.f, s2 = 0.f, s3 = 0.f;
#pragma unroll
    for (int j = 0; j < 64; j += 4) {
        s0 += scr[wave][lane][(lane + j + 0) & 63];
        s1 += scr[wave][lane][(lane + j + 1) & 63];
        s2 += scr[wave][lane][(lane + j + 2) & 63];
        s3 += scr[wave][lane][(lane + j + 3) & 63];
    }
    const float logit = (s0 + s1) + (s2 + s3);

    const int t     = lane >> 3;
    const int e     = lane & 7;
    const int token = tok0 + t;

    float* out_idx    = out;                 // [TOKENS][2] (indices stored as fp32)
    float* out_gate   = out + TOKENS * 2;    // [TOKENS][2]
    float* out_logits = out + TOKENS * 4;    // [TOKENS][8]

    // logits store: address = tok0*8 + lane -> fully coalesced
    out_logits[(size_t)token * E + e] = logit;

    // Top-2 across the 8 lanes of this token (xor masks 1,2,4 stay in-group).
    float v1 = logit, v2 = -INFINITY;
    int   i1 = e,     i2 = E;
#pragma unroll
    for (int m = 1; m <= 4; m <<= 1) {
        float ov1 = __shfl_xor(v1, m, 64);
        int   oi1 = __shfl_xor(i1, m, 64);
        float ov2 = __shfl_xor(v2, m, 64);
        int   oi2 = __shfl_xor(i2, m, 64);
        float nv1, nv2; int ni1, ni2;
        if (better(v1, i1, ov1, oi1)) {
            nv1 = v1; ni1 = i1;
            if (better(v2, i2, ov1, oi1)) { nv2 = v2;  ni2 = i2;  }
            else                          { nv2 = ov1; ni2 = oi1; }
        } else {
            nv1 = ov1; ni1 = oi1;
            if (better(ov2, oi2, v1, i1)) { nv2 = ov2; ni2 = oi2; }
            else                          { nv2 = v1;  ni2 = i1;  }
        }
        v1 = nv1; i1 = ni1; v2 = nv2; i2 = ni2;
    }

    // softmax over the 2 selected logits: [1, e^(v2-v1)] / (1 + e^(v2-v1))
    if (e < 2) {
        const float ed  = expf(v2 - v1);          // v2 <= v1, so ed in (0,1]
        const float inv = 1.0f / (1.0f + ed);
        const float g   = (e == 0) ? inv : ed * inv;
        out_idx [token * 2 + e] = (float)((e == 0) ? i1 : i2);
        out_gate[token * 2 + e] = g;
    }
}

extern "C" void kernel_launch(void* const* d_in, const int* in_sizes, int n_in,
                              void* d_out, int out_size, void* d_ws, size_t ws_size,
                              hipStream_t stream) {
    const float* x = (const float*)d_in[0];
    const float* w = (const float*)d_in[1];
    float* out = (float*)d_out;
    // 16384 tokens / (4 waves * 8 tokens) = 512 blocks, 256 threads each.
    hipLaunchKernelGGL(moe_router_kernel, dim3(512), dim3(256), 0, stream,
                       x, w, out);
}